// Round 5
// baseline (974.294 us; speedup 1.0000x reference)
//
#include <hip/hip_runtime.h>
#include <stdint.h>

#define TPB 1024
#define NJ 8           // float4 chunks per thread: 1024*8*4 = 32768 = H
#define HSZ 32768
#define NW (TPB / 64)  // 16 waves
#define CAP 1024       // candidate capacity (threshold bin ~30 elems for N(0,1))

// LDS-only barrier: orders LDS (lgkmcnt) but leaves global loads in flight
// (plain __syncthreads() drains vmcnt(0), which would kill the row prefetch).
#define BARRIER() do { \
    asm volatile("s_waitcnt lgkmcnt(0)" ::: "memory"); \
    __builtin_amdgcn_s_barrier(); \
} while (0)

// order-preserving float->uint key: bigger float => bigger key
__device__ __forceinline__ uint32_t f2k(float f) {
    uint32_t u = __float_as_uint(f);
    return u ^ (0x80000000u | (uint32_t)(-(int32_t)(u >> 31)));
}

struct Sm {
    uint32_t hist[4096];
    uint32_t wtot[NW];
    uint32_t cand_key[CAP];
    uint32_t cand_col[CAP];
    uint32_t bin, rem, eqcnt, ncand, chunk_base;
};

// Suffix-select over hist[4096] (descending bins = larger values).
// Finds bin B with count(>B) < need <= count(>=B); sm.bin=B, sm.rem=need-count(>B).
__device__ __forceinline__ void select4096(Sm& sm, uint32_t need, int t) {
    const int lane = t & 63, wid = t >> 6;
    uint32_t b[4], pt = 0;
#pragma unroll
    for (int jj = 0; jj < 4; ++jj) { b[jj] = sm.hist[t * 4 + jj]; pt += b[jj]; }
    uint32_t pre = pt;  // wave suffix-inclusive scan
#pragma unroll
    for (int off = 1; off < 64; off <<= 1) {
        uint32_t n = (uint32_t)__shfl_down((int)pre, off, 64);
        if (lane + off < 64) pre += n;
    }
    if (lane == 0) sm.wtot[wid] = pre;
    BARRIER();
    uint32_t wsuf = 0;
    for (int w = wid + 1; w < NW; ++w) wsuf += sm.wtot[w];
    const uint32_t Sincl = pre + wsuf;
    const uint32_t Sexcl = Sincl - pt;
    if (Sexcl < need && Sincl >= need) {
        uint32_t run = Sexcl;
#pragma unroll
        for (int jj = 3; jj >= 0; --jj) {
            if (run + b[jj] >= need) { sm.bin = (uint32_t)(t * 4 + jj); sm.rem = need - run; break; }
            run += b[jj];
        }
    }
    BARRIER();
}

// Same over hist[256]; also reports count of the selected bin.
__device__ __forceinline__ void select256(Sm& sm, uint32_t need, int t) {
    const int lane = t & 63, wid = t >> 6;
    uint32_t pt = (t < 256) ? sm.hist[t] : 0u;
    uint32_t pre = pt;
#pragma unroll
    for (int off = 1; off < 64; off <<= 1) {
        uint32_t n = (uint32_t)__shfl_down((int)pre, off, 64);
        if (lane + off < 64) pre += n;
    }
    if (lane == 0) sm.wtot[wid] = pre;
    BARRIER();
    uint32_t wsuf = 0;
    for (int w = wid + 1; w < NW; ++w) wsuf += sm.wtot[w];
    const uint32_t Sincl = pre + wsuf;
    const uint32_t Sexcl = Sincl - pt;
    if (t < 256 && Sexcl < need && Sincl >= need) {
        sm.bin = (uint32_t)t; sm.rem = need - Sexcl; sm.eqcnt = pt;
    }
    BARRIER();
}

__device__ __forceinline__ void load_row(float4 (&dst)[NJ], const float* __restrict__ x,
                                         int r, int t) {
    const float4* p = reinterpret_cast<const float4*>(x + (size_t)r * HSZ);
#pragma unroll
    for (int j = 0; j < NJ; ++j) dst[j] = p[j * TPB + t];
}

__device__ __forceinline__ void process_row(const float4 (&vv)[NJ], float* __restrict__ outr,
                                            uint32_t k, Sm& sm, int t) {
    float4* outr4 = reinterpret_cast<float4*>(outr);

    // ===== level-1 histogram (key bits [31:20]) =====
#pragma unroll
    for (int i = 0; i < 4096 / TPB; ++i) sm.hist[i * TPB + t] = 0u;
    if (t == 0) sm.ncand = 0u;
    BARRIER();
#pragma unroll
    for (int j = 0; j < NJ; ++j) {
        atomicAdd(&sm.hist[f2k(vv[j].x) >> 20], 1u);
        atomicAdd(&sm.hist[f2k(vv[j].y) >> 20], 1u);
        atomicAdd(&sm.hist[f2k(vv[j].z) >> 20], 1u);
        atomicAdd(&sm.hist[f2k(vv[j].w) >> 20], 1u);
    }
    BARRIER();
    select4096(sm, k, t);
    const uint32_t B1 = sm.bin;
    const uint32_t need2 = sm.rem;

    // ===== candidate compaction from registers (no global writes yet) =====
#pragma unroll
    for (int j = 0; j < NJ; ++j) {
        float vals[4] = { vv[j].x, vv[j].y, vv[j].z, vv[j].w };
#pragma unroll
        for (int c = 0; c < 4; ++c) {
            uint32_t key = f2k(vals[c]);
            if ((key >> 20) == B1) {
                uint32_t pos = atomicAdd(&sm.ncand, 1u);
                if (pos < CAP) {
                    sm.cand_key[pos] = key;
                    sm.cand_col[pos] = (uint32_t)((j * TPB + t) * 4 + c);
                }
            }
        }
    }
    BARRIER();
    const uint32_t C = sm.ncand;

    uint32_t K, eqneed, eqcnt;
    if (C <= CAP) {
        // ===== refine among C candidates (tiny) =====
        // level 2: bits [19:8]
#pragma unroll
        for (int i = 0; i < 4096 / TPB; ++i) sm.hist[i * TPB + t] = 0u;
        BARRIER();
        for (uint32_t i = t; i < C; i += TPB)
            atomicAdd(&sm.hist[(sm.cand_key[i] >> 8) & 0xFFFu], 1u);
        BARRIER();
        select4096(sm, need2, t);
        const uint32_t B2 = sm.bin;
        const uint32_t need3 = sm.rem;

        // level 3: bits [7:0]
        if (t < 256) sm.hist[t] = 0u;
        BARRIER();
        const uint32_t pref = (B1 << 12) | B2;
        for (uint32_t i = t; i < C; i += TPB)
            if ((sm.cand_key[i] >> 8) == pref) atomicAdd(&sm.hist[sm.cand_key[i] & 0xFFu], 1u);
        BARRIER();
        select256(sm, need3, t);
        K = (pref << 8) | sm.bin;
        eqneed = sm.rem;
        eqcnt = sm.eqcnt;
    } else {
        // ===== fallback refine from registers (overflow — not expected) =====
#pragma unroll
        for (int i = 0; i < 4096 / TPB; ++i) sm.hist[i * TPB + t] = 0u;
        BARRIER();
#pragma unroll
        for (int j = 0; j < NJ; ++j) {
            float vals[4] = { vv[j].x, vv[j].y, vv[j].z, vv[j].w };
#pragma unroll
            for (int c = 0; c < 4; ++c) {
                uint32_t key = f2k(vals[c]);
                if ((key >> 20) == B1) atomicAdd(&sm.hist[(key >> 8) & 0xFFFu], 1u);
            }
        }
        BARRIER();
        select4096(sm, need2, t);
        const uint32_t B2 = sm.bin;
        const uint32_t need3 = sm.rem;

        if (t < 256) sm.hist[t] = 0u;
        BARRIER();
        const uint32_t pref = (B1 << 12) | B2;
#pragma unroll
        for (int j = 0; j < NJ; ++j) {
            float vals[4] = { vv[j].x, vv[j].y, vv[j].z, vv[j].w };
#pragma unroll
            for (int c = 0; c < 4; ++c) {
                uint32_t key = f2k(vals[c]);
                if ((key >> 8) == pref) atomicAdd(&sm.hist[key & 0xFFu], 1u);
            }
        }
        BARRIER();
        select256(sm, need3, t);
        K = (pref << 8) | sm.bin;
        eqneed = sm.rem;
        eqcnt = sm.eqcnt;
    }

    // ===== single final write pass: each element stored exactly once =====
    if (eqcnt == eqneed) {
        // all elements == K selected: out = (key >= K) ? v : 0
#pragma unroll
        for (int j = 0; j < NJ; ++j) {
            float vals[4] = { vv[j].x, vv[j].y, vv[j].z, vv[j].w };
            float ov[4];
#pragma unroll
            for (int c = 0; c < 4; ++c)
                ov[c] = (f2k(vals[c]) >= K) ? vals[c] : 0.0f;
            float4 o; o.x = ov[0]; o.y = ov[1]; o.z = ov[2]; o.w = ov[3];
            outr4[j * TPB + t] = o;
        }
    } else if (C <= CAP) {
        // rare ties: rank each own ==K element against the candidate list
#pragma unroll
        for (int j = 0; j < NJ; ++j) {
            float vals[4] = { vv[j].x, vv[j].y, vv[j].z, vv[j].w };
            float ov[4];
#pragma unroll
            for (int c = 0; c < 4; ++c) {
                uint32_t key = f2k(vals[c]);
                bool take = key > K;
                if (key == K) {
                    uint32_t col = (uint32_t)((j * TPB + t) * 4 + c);
                    uint32_t rank = 0;
                    for (uint32_t m = 0; m < C; ++m)
                        if (sm.cand_key[m] == K && sm.cand_col[m] < col) ++rank;
                    take = (rank < eqneed);
                }
                ov[c] = take ? vals[c] : 0.0f;
            }
            float4 o; o.x = ov[0]; o.y = ov[1]; o.z = ov[2]; o.w = ov[3];
            outr4[j * TPB + t] = o;
        }
    } else {
        // overflow + ties: ordered selection among ==K by lowest column, chunked
        if (t == 0) sm.chunk_base = 0u;
        BARRIER();
        const int lane = t & 63;
        const int wid = t >> 6;
        for (int j = 0; j < NJ; ++j) {
            float vals[4] = { vv[j].x, vv[j].y, vv[j].z, vv[j].w };
            uint32_t keys[4];
            uint32_t e = 0;
#pragma unroll
            for (int c = 0; c < 4; ++c) { keys[c] = f2k(vals[c]); e += (keys[c] == K) ? 1u : 0u; }
            uint32_t pre = e;
            for (int off = 1; off < 64; off <<= 1) {
                uint32_t n = (uint32_t)__shfl_up((int)pre, off, 64);
                if (lane >= off) pre += n;
            }
            if (lane == 63) sm.wtot[wid] = pre;
            BARRIER();
            uint32_t before = sm.chunk_base + (pre - e);
            for (int w = 0; w < wid; ++w) before += sm.wtot[w];
            float ov[4];
#pragma unroll
            for (int c = 0; c < 4; ++c) {
                bool take = keys[c] > K;
                if (keys[c] == K) { take = (before < eqneed); ++before; }
                ov[c] = take ? vals[c] : 0.0f;
            }
            float4 o; o.x = ov[0]; o.y = ov[1]; o.z = ov[2]; o.w = ov[3];
            outr4[j * TPB + t] = o;
            BARRIER();
            if (t == 0) {
                uint32_t s2 = sm.chunk_base;
#pragma unroll
                for (int w = 0; w < NW; ++w) s2 += sm.wtot[w];
                sm.chunk_base = s2;
            }
            BARRIER();
        }
    }
}

// __launch_bounds__(TPB, 1): 16 waves/block = 4 waves/SIMD -> VGPR cap 128.
// (TPB, 4) empirically forced a 64-VGPR cap and spilled the 64-reg ping-pong
// buffers (round-3 WRITE_SIZE 3.7 GB vs 1.07 ideal).
__global__ __launch_bounds__(TPB, 1) void topk_scatter_kernel(
    const float* __restrict__ x,
    const int* __restrict__ kp,
    float* __restrict__ out,
    int nrows)
{
    __shared__ Sm sm;
    const int t = threadIdx.x;
    const uint32_t k = (uint32_t)kp[0];
    const int gs = (int)gridDim.x;

    if (k == 0u || k >= (uint32_t)HSZ) {  // degenerate: all zeros or identity
        for (int r = (int)blockIdx.x; r < nrows; r += gs) {
            const float4* xr4 = reinterpret_cast<const float4*>(x + (size_t)r * HSZ);
            float4* outr4 = reinterpret_cast<float4*>(out + (size_t)r * HSZ);
#pragma unroll
            for (int j = 0; j < NJ; ++j) {
                float4 o;
                if (k == 0u) { o.x = o.y = o.z = o.w = 0.0f; }
                else o = xr4[j * TPB + t];
                outr4[j * TPB + t] = o;
            }
        }
        return;
    }

    // ===== ping-pong pipelined row loop: prefetch r+gs while processing r =====
    int r = (int)blockIdx.x;
    if (r >= nrows) return;
    float4 va[NJ], vb[NJ];
    load_row(va, x, r, t);
    for (;;) {
        const int rB = r + gs;
        if (rB < nrows) load_row(vb, x, rB, t);      // prefetch (stays in flight)
        process_row(va, out + (size_t)r * HSZ, k, sm, t);
        if (rB >= nrows) return;

        const int rC = rB + gs;
        if (rC < nrows) load_row(va, x, rC, t);      // prefetch
        process_row(vb, out + (size_t)rB * HSZ, k, sm, t);
        if (rC >= nrows) return;
        r = rC;
    }
}

extern "C" void kernel_launch(void* const* d_in, const int* in_sizes, int n_in,
                              void* d_out, int out_size, void* d_ws, size_t ws_size,
                              hipStream_t stream) {
    const float* x = (const float*)d_in[0];
    const int* kp = (const int*)d_in[1];
    float* out = (float*)d_out;
    const int total = in_sizes[0];
    const int rows = total / HSZ;     // 8192
    int grid = rows < 256 ? rows : 256;  // 1 persistent block per CU
    topk_scatter_kernel<<<grid, TPB, 0, stream>>>(x, kp, out, rows);
}

// Round 6
// 727.484 us; speedup vs baseline: 1.3393x; 1.3393x over previous
//
#include <hip/hip_runtime.h>
#include <stdint.h>

#define TPB 1024
#define NJ 8           // float4 chunks per thread: 1024*8*4 = 32768 = H
#define HSZ 32768
#define NW (TPB / 64)  // 16 waves
#define CAP 1024       // candidate capacity (threshold bin ~30 elems for N(0,1))

// LDS-only barrier: orders LDS (lgkmcnt) but leaves global loads in flight
// (plain __syncthreads() drains vmcnt(0), which would kill the row prefetch).
#define BARRIER() do { \
    asm volatile("s_waitcnt lgkmcnt(0)" ::: "memory"); \
    __builtin_amdgcn_s_barrier(); \
} while (0)

// order-preserving float->uint key: bigger float => bigger key
__device__ __forceinline__ uint32_t f2k(float f) {
    uint32_t u = __float_as_uint(f);
    return u ^ (0x80000000u | (uint32_t)(-(int32_t)(u >> 31)));
}

struct Sm {
    float4 row[HSZ / 4];        // 128 KB: the resident row
    uint32_t hist[4096];        // 16 KB
    uint32_t wtot[NW];
    uint32_t cand_key[CAP];     // 4 KB
    uint32_t cand_col[CAP];     // 4 KB
    uint32_t bin, rem, eqcnt, ncand, chunk_base;
};                              // ~152 KB total (<160 KB/CU on gfx950)

// Suffix-select over hist[4096] (descending bins = larger values).
// Finds bin B with count(>B) < need <= count(>=B); sm.bin=B, sm.rem=need-count(>B).
__device__ __forceinline__ void select4096(Sm& sm, uint32_t need, int t) {
    const int lane = t & 63, wid = t >> 6;
    uint32_t b[4], pt = 0;
#pragma unroll
    for (int jj = 0; jj < 4; ++jj) { b[jj] = sm.hist[t * 4 + jj]; pt += b[jj]; }
    uint32_t pre = pt;  // wave suffix-inclusive scan
#pragma unroll
    for (int off = 1; off < 64; off <<= 1) {
        uint32_t n = (uint32_t)__shfl_down((int)pre, off, 64);
        if (lane + off < 64) pre += n;
    }
    if (lane == 0) sm.wtot[wid] = pre;
    BARRIER();
    uint32_t wsuf = 0;
    for (int w = wid + 1; w < NW; ++w) wsuf += sm.wtot[w];
    const uint32_t Sincl = pre + wsuf;
    const uint32_t Sexcl = Sincl - pt;
    if (Sexcl < need && Sincl >= need) {
        uint32_t run = Sexcl;
#pragma unroll
        for (int jj = 3; jj >= 0; --jj) {
            if (run + b[jj] >= need) { sm.bin = (uint32_t)(t * 4 + jj); sm.rem = need - run; break; }
            run += b[jj];
        }
    }
    BARRIER();
}

// Same over hist[256]; also reports count of the selected bin.
__device__ __forceinline__ void select256(Sm& sm, uint32_t need, int t) {
    const int lane = t & 63, wid = t >> 6;
    uint32_t pt = (t < 256) ? sm.hist[t] : 0u;
    uint32_t pre = pt;
#pragma unroll
    for (int off = 1; off < 64; off <<= 1) {
        uint32_t n = (uint32_t)__shfl_down((int)pre, off, 64);
        if (lane + off < 64) pre += n;
    }
    if (lane == 0) sm.wtot[wid] = pre;
    BARRIER();
    uint32_t wsuf = 0;
    for (int w = wid + 1; w < NW; ++w) wsuf += sm.wtot[w];
    const uint32_t Sincl = pre + wsuf;
    const uint32_t Sexcl = Sincl - pt;
    if (t < 256 && Sexcl < need && Sincl >= need) {
        sm.bin = (uint32_t)t; sm.rem = need - Sexcl; sm.eqcnt = pt;
    }
    BARRIER();
}

// Process the row currently resident in sm.row (LDS); writes final output.
__device__ __forceinline__ void process_row(float* __restrict__ outr,
                                            uint32_t k, Sm& sm, int t) {
    float4* outr4 = reinterpret_cast<float4*>(outr);

    // ===== phase A: level-1 histogram (key bits [31:20]) from LDS =====
#pragma unroll
    for (int i = 0; i < 4096 / TPB; ++i) sm.hist[i * TPB + t] = 0u;
    if (t == 0) sm.ncand = 0u;
    BARRIER();
#pragma unroll
    for (int j = 0; j < NJ; ++j) {
        float4 v = sm.row[j * TPB + t];
        atomicAdd(&sm.hist[f2k(v.x) >> 20], 1u);
        atomicAdd(&sm.hist[f2k(v.y) >> 20], 1u);
        atomicAdd(&sm.hist[f2k(v.z) >> 20], 1u);
        atomicAdd(&sm.hist[f2k(v.w) >> 20], 1u);
    }
    BARRIER();
    select4096(sm, k, t);
    const uint32_t B1 = sm.bin;
    const uint32_t need2 = sm.rem;

    // ===== phase B: candidate compaction from LDS =====
#pragma unroll
    for (int j = 0; j < NJ; ++j) {
        float4 v = sm.row[j * TPB + t];
        float vals[4] = { v.x, v.y, v.z, v.w };
#pragma unroll
        for (int c = 0; c < 4; ++c) {
            uint32_t key = f2k(vals[c]);
            if ((key >> 20) == B1) {
                uint32_t pos = atomicAdd(&sm.ncand, 1u);
                if (pos < CAP) {
                    sm.cand_key[pos] = key;
                    sm.cand_col[pos] = (uint32_t)((j * TPB + t) * 4 + c);
                }
            }
        }
    }
    BARRIER();
    const uint32_t C = sm.ncand;

    uint32_t K, eqneed, eqcnt;
    if (C <= CAP) {
        // ===== refine among C candidates (tiny) =====
#pragma unroll
        for (int i = 0; i < 4096 / TPB; ++i) sm.hist[i * TPB + t] = 0u;
        BARRIER();
        for (uint32_t i = t; i < C; i += TPB)
            atomicAdd(&sm.hist[(sm.cand_key[i] >> 8) & 0xFFFu], 1u);
        BARRIER();
        select4096(sm, need2, t);
        const uint32_t B2 = sm.bin;
        const uint32_t need3 = sm.rem;

        if (t < 256) sm.hist[t] = 0u;
        BARRIER();
        const uint32_t pref = (B1 << 12) | B2;
        for (uint32_t i = t; i < C; i += TPB)
            if ((sm.cand_key[i] >> 8) == pref) atomicAdd(&sm.hist[sm.cand_key[i] & 0xFFu], 1u);
        BARRIER();
        select256(sm, need3, t);
        K = (pref << 8) | sm.bin;
        eqneed = sm.rem;
        eqcnt = sm.eqcnt;
    } else {
        // ===== fallback refine from LDS row (overflow — not expected) =====
#pragma unroll
        for (int i = 0; i < 4096 / TPB; ++i) sm.hist[i * TPB + t] = 0u;
        BARRIER();
#pragma unroll
        for (int j = 0; j < NJ; ++j) {
            float4 v = sm.row[j * TPB + t];
            float vals[4] = { v.x, v.y, v.z, v.w };
#pragma unroll
            for (int c = 0; c < 4; ++c) {
                uint32_t key = f2k(vals[c]);
                if ((key >> 20) == B1) atomicAdd(&sm.hist[(key >> 8) & 0xFFFu], 1u);
            }
        }
        BARRIER();
        select4096(sm, need2, t);
        const uint32_t B2 = sm.bin;
        const uint32_t need3 = sm.rem;

        if (t < 256) sm.hist[t] = 0u;
        BARRIER();
        const uint32_t pref = (B1 << 12) | B2;
#pragma unroll
        for (int j = 0; j < NJ; ++j) {
            float4 v = sm.row[j * TPB + t];
            float vals[4] = { v.x, v.y, v.z, v.w };
#pragma unroll
            for (int c = 0; c < 4; ++c) {
                uint32_t key = f2k(vals[c]);
                if ((key >> 8) == pref) atomicAdd(&sm.hist[key & 0xFFu], 1u);
            }
        }
        BARRIER();
        select256(sm, need3, t);
        K = (pref << 8) | sm.bin;
        eqneed = sm.rem;
        eqcnt = sm.eqcnt;
    }

    // ===== phase C: single final write pass from LDS =====
    if (eqcnt == eqneed) {
#pragma unroll
        for (int j = 0; j < NJ; ++j) {
            float4 v = sm.row[j * TPB + t];
            float vals[4] = { v.x, v.y, v.z, v.w };
            float ov[4];
#pragma unroll
            for (int c = 0; c < 4; ++c)
                ov[c] = (f2k(vals[c]) >= K) ? vals[c] : 0.0f;
            float4 o; o.x = ov[0]; o.y = ov[1]; o.z = ov[2]; o.w = ov[3];
            outr4[j * TPB + t] = o;
        }
    } else if (C <= CAP) {
        // rare ties: rank own ==K elements against the candidate list
#pragma unroll
        for (int j = 0; j < NJ; ++j) {
            float4 v = sm.row[j * TPB + t];
            float vals[4] = { v.x, v.y, v.z, v.w };
            float ov[4];
#pragma unroll
            for (int c = 0; c < 4; ++c) {
                uint32_t key = f2k(vals[c]);
                bool take = key > K;
                if (key == K) {
                    uint32_t col = (uint32_t)((j * TPB + t) * 4 + c);
                    uint32_t rank = 0;
                    for (uint32_t m = 0; m < C; ++m)
                        if (sm.cand_key[m] == K && sm.cand_col[m] < col) ++rank;
                    take = (rank < eqneed);
                }
                ov[c] = take ? vals[c] : 0.0f;
            }
            float4 o; o.x = ov[0]; o.y = ov[1]; o.z = ov[2]; o.w = ov[3];
            outr4[j * TPB + t] = o;
        }
    } else {
        // overflow + ties: ordered selection among ==K by lowest column, chunked
        if (t == 0) sm.chunk_base = 0u;
        BARRIER();
        const int lane = t & 63;
        const int wid = t >> 6;
        for (int j = 0; j < NJ; ++j) {
            float4 v = sm.row[j * TPB + t];
            float vals[4] = { v.x, v.y, v.z, v.w };
            uint32_t keys[4];
            uint32_t e = 0;
#pragma unroll
            for (int c = 0; c < 4; ++c) { keys[c] = f2k(vals[c]); e += (keys[c] == K) ? 1u : 0u; }
            uint32_t pre = e;
            for (int off = 1; off < 64; off <<= 1) {
                uint32_t n = (uint32_t)__shfl_up((int)pre, off, 64);
                if (lane >= off) pre += n;
            }
            if (lane == 63) sm.wtot[wid] = pre;
            BARRIER();
            uint32_t before = sm.chunk_base + (pre - e);
            for (int w = 0; w < wid; ++w) before += sm.wtot[w];
            float ov[4];
#pragma unroll
            for (int c = 0; c < 4; ++c) {
                bool take = keys[c] > K;
                if (keys[c] == K) { take = (before < eqneed); ++before; }
                ov[c] = take ? vals[c] : 0.0f;
            }
            float4 o; o.x = ov[0]; o.y = ov[1]; o.z = ov[2]; o.w = ov[3];
            outr4[j * TPB + t] = o;
            BARRIER();
            if (t == 0) {
                uint32_t s2 = sm.chunk_base;
#pragma unroll
                for (int w = 0; w < NW; ++w) s2 += sm.wtot[w];
                sm.chunk_base = s2;
            }
            BARRIER();
        }
    }
}

__global__ __launch_bounds__(TPB) void topk_scatter_kernel(
    const float* __restrict__ x,
    const int* __restrict__ kp,
    float* __restrict__ out,
    int nrows)
{
    __shared__ Sm sm;
    const int t = threadIdx.x;
    const uint32_t k = (uint32_t)kp[0];
    const int gs = (int)gridDim.x;

    if (k == 0u || k >= (uint32_t)HSZ) {  // degenerate: all zeros or identity
        for (int r = (int)blockIdx.x; r < nrows; r += gs) {
            const float4* xr4 = reinterpret_cast<const float4*>(x + (size_t)r * HSZ);
            float4* outr4 = reinterpret_cast<float4*>(out + (size_t)r * HSZ);
#pragma unroll
            for (int j = 0; j < NJ; ++j) {
                float4 o;
                if (k == 0u) { o.x = o.y = o.z = o.w = 0.0f; }
                else o = xr4[j * TPB + t];
                outr4[j * TPB + t] = o;
            }
        }
        return;
    }

    int r = (int)blockIdx.x;
    if (r >= nrows) return;

    float4 g[NJ];  // single 32-VGPR prefetch buffer (round-2-proven pressure)

    // prologue: load row r -> regs -> LDS
    {
        const float4* p = reinterpret_cast<const float4*>(x + (size_t)r * HSZ);
#pragma unroll
        for (int j = 0; j < NJ; ++j) g[j] = p[j * TPB + t];
        asm volatile("s_waitcnt vmcnt(0)" ::: "memory");
#pragma unroll
        for (int j = 0; j < NJ; ++j) sm.row[j * TPB + t] = g[j];
        BARRIER();
    }

    for (;;) {
        const int rn = r + gs;
        if (rn < nrows) {
            // prefetch next row into g; stays in flight across all lgkm-only
            // barriers in process_row (asm memory clobbers pin issue order).
            const float4* p = reinterpret_cast<const float4*>(x + (size_t)rn * HSZ);
#pragma unroll
            for (int j = 0; j < NJ; ++j) g[j] = p[j * TPB + t];
        }
        process_row(out + (size_t)r * HSZ, k, sm, t);
        if (rn >= nrows) break;

        BARRIER();  // all waves done reading sm.row for row r
        asm volatile("s_waitcnt vmcnt(0)" ::: "memory");  // prefetch arrived
#pragma unroll
        for (int j = 0; j < NJ; ++j) sm.row[j * TPB + t] = g[j];
        BARRIER();  // row rn visible to all waves
        r = rn;
    }
}

extern "C" void kernel_launch(void* const* d_in, const int* in_sizes, int n_in,
                              void* d_out, int out_size, void* d_ws, size_t ws_size,
                              hipStream_t stream) {
    const float* x = (const float*)d_in[0];
    const int* kp = (const int*)d_in[1];
    float* out = (float*)d_out;
    const int total = in_sizes[0];
    const int rows = total / HSZ;        // 8192
    int grid = rows < 256 ? rows : 256;  // 1 persistent block per CU (LDS-bound)
    topk_scatter_kernel<<<grid, TPB, 0, stream>>>(x, kp, out, rows);
}

// Round 7
// 551.543 us; speedup vs baseline: 1.7665x; 1.3190x over previous
//
#include <hip/hip_runtime.h>
#include <stdint.h>

#define TPB 1024
#define HSZ 32768
#define NCH 8              // chunks per row
#define CHF4 1024          // float4 per chunk (16 KB); CHF4 == TPB
#define NW (TPB / 64)      // 16 waves
#define CAP 1024           // candidate capacity (threshold bin ~40 elems for N(0,1))

// LDS-only barrier: orders LDS (lgkmcnt) but leaves global/DMA loads in flight.
#define BARRIER() do { \
    asm volatile("s_waitcnt lgkmcnt(0)" ::: "memory"); \
    __builtin_amdgcn_s_barrier(); \
} while (0)

// Row-start barrier: also drains DMA arrivals (and prior row's store acks).
#define WAIT_VM0_BARRIER() do { \
    asm volatile("s_waitcnt vmcnt(0) lgkmcnt(0)" ::: "memory"); \
    __builtin_amdgcn_s_barrier(); \
} while (0)

// order-preserving float->uint key: bigger float => bigger key
__device__ __forceinline__ uint32_t f2k(float f) {
    uint32_t u = __float_as_uint(f);
    return u ^ (0x80000000u | (uint32_t)(-(int32_t)(u >> 31)));
}

struct Sm {
    float4 row[NCH * CHF4];     // 128 KB resident row (8 recyclable chunks)
    uint32_t hist[4096];        // 16 KB
    uint32_t wtot[NW];
    uint32_t cand_key[CAP];     // 4 KB
    uint32_t cand_col[CAP];     // 4 KB
    uint32_t bin, rem, eqcnt, ncand, chunk_base;
};                              // ~152 KB (<160 KB/CU; 156160 launched OK in r5)

// DMA one 16 KB chunk of a row: global -> LDS slot c, no VGPR staging.
// Per-lane LDS dst = slot + t*16 (lane-contiguous, linear — required layout).
__device__ __forceinline__ void dma_chunk(const float* __restrict__ xrow, Sm& sm,
                                          int c, int t) {
    const uint32_t* g = (const uint32_t*)xrow + (size_t)c * (CHF4 * 4) + (size_t)t * 4;
    uint32_t* l = (uint32_t*)(sm.row + c * CHF4 + t);
    __builtin_amdgcn_global_load_lds(
        (const __attribute__((address_space(1))) uint32_t*)g,
        (__attribute__((address_space(3))) uint32_t*)l,
        16, 0, 0);
}

// Suffix-select over hist[4096] (descending bins = larger values).
__device__ __forceinline__ void select4096(Sm& sm, uint32_t need, int t) {
    const int lane = t & 63, wid = t >> 6;
    uint32_t b[4], pt = 0;
#pragma unroll
    for (int jj = 0; jj < 4; ++jj) { b[jj] = sm.hist[t * 4 + jj]; pt += b[jj]; }
    uint32_t pre = pt;  // wave suffix-inclusive scan
#pragma unroll
    for (int off = 1; off < 64; off <<= 1) {
        uint32_t n = (uint32_t)__shfl_down((int)pre, off, 64);
        if (lane + off < 64) pre += n;
    }
    if (lane == 0) sm.wtot[wid] = pre;
    BARRIER();
    uint32_t wsuf = 0;
    for (int w = wid + 1; w < NW; ++w) wsuf += sm.wtot[w];
    const uint32_t Sincl = pre + wsuf;
    const uint32_t Sexcl = Sincl - pt;
    if (Sexcl < need && Sincl >= need) {
        uint32_t run = Sexcl;
#pragma unroll
        for (int jj = 3; jj >= 0; --jj) {
            if (run + b[jj] >= need) { sm.bin = (uint32_t)(t * 4 + jj); sm.rem = need - run; break; }
            run += b[jj];
        }
    }
    BARRIER();
}

// Same over hist[256]; also reports count of the selected bin.
__device__ __forceinline__ void select256(Sm& sm, uint32_t need, int t) {
    const int lane = t & 63, wid = t >> 6;
    uint32_t pt = (t < 256) ? sm.hist[t] : 0u;
    uint32_t pre = pt;
#pragma unroll
    for (int off = 1; off < 64; off <<= 1) {
        uint32_t n = (uint32_t)__shfl_down((int)pre, off, 64);
        if (lane + off < 64) pre += n;
    }
    if (lane == 0) sm.wtot[wid] = pre;
    BARRIER();
    uint32_t wsuf = 0;
    for (int w = wid + 1; w < NW; ++w) wsuf += sm.wtot[w];
    const uint32_t Sincl = pre + wsuf;
    const uint32_t Sexcl = Sincl - pt;
    if (t < 256 && Sexcl < need && Sincl >= need) {
        sm.bin = (uint32_t)t; sm.rem = need - Sexcl; sm.eqcnt = pt;
    }
    BARRIER();
}

// Process row resident in sm.row; write final output; during phase C, recycle
// each chunk slot as the DMA landing buffer for the next row (xnext != null).
__device__ __forceinline__ void process_row(float* __restrict__ outr,
                                            const float* __restrict__ xnext,
                                            uint32_t k, Sm& sm, int t) {
    float4* outr4 = reinterpret_cast<float4*>(outr);

    // ===== phase A: level-1 histogram (key bits [31:20]) =====
#pragma unroll
    for (int i = 0; i < 4096 / TPB; ++i) sm.hist[i * TPB + t] = 0u;
    if (t == 0) sm.ncand = 0u;
    BARRIER();
#pragma unroll
    for (int c = 0; c < NCH; ++c) {
        float4 v = sm.row[c * CHF4 + t];
        atomicAdd(&sm.hist[f2k(v.x) >> 20], 1u);
        atomicAdd(&sm.hist[f2k(v.y) >> 20], 1u);
        atomicAdd(&sm.hist[f2k(v.z) >> 20], 1u);
        atomicAdd(&sm.hist[f2k(v.w) >> 20], 1u);
    }
    BARRIER();
    select4096(sm, k, t);
    const uint32_t B1 = sm.bin;
    const uint32_t need2 = sm.rem;

    // ===== phase B: candidate compaction =====
#pragma unroll
    for (int c = 0; c < NCH; ++c) {
        float4 v = sm.row[c * CHF4 + t];
        float vals[4] = { v.x, v.y, v.z, v.w };
#pragma unroll
        for (int e = 0; e < 4; ++e) {
            uint32_t key = f2k(vals[e]);
            if ((key >> 20) == B1) {
                uint32_t pos = atomicAdd(&sm.ncand, 1u);
                if (pos < CAP) {
                    sm.cand_key[pos] = key;
                    sm.cand_col[pos] = (uint32_t)((c * CHF4 + t) * 4 + e);
                }
            }
        }
    }
    BARRIER();
    const uint32_t C = sm.ncand;

    uint32_t K, eqneed, eqcnt;
    if (C <= CAP) {
        // ===== refine among C candidates (tiny; row slots untouched) =====
#pragma unroll
        for (int i = 0; i < 4096 / TPB; ++i) sm.hist[i * TPB + t] = 0u;
        BARRIER();
        for (uint32_t i = t; i < C; i += TPB)
            atomicAdd(&sm.hist[(sm.cand_key[i] >> 8) & 0xFFFu], 1u);
        BARRIER();
        select4096(sm, need2, t);
        const uint32_t B2 = sm.bin;
        const uint32_t need3 = sm.rem;

        if (t < 256) sm.hist[t] = 0u;
        BARRIER();
        const uint32_t pref = (B1 << 12) | B2;
        for (uint32_t i = t; i < C; i += TPB)
            if ((sm.cand_key[i] >> 8) == pref) atomicAdd(&sm.hist[sm.cand_key[i] & 0xFFu], 1u);
        BARRIER();
        select256(sm, need3, t);
        K = (pref << 8) | sm.bin;
        eqneed = sm.rem;
        eqcnt = sm.eqcnt;
    } else {
        // ===== fallback refine from LDS row (overflow — not expected) =====
#pragma unroll
        for (int i = 0; i < 4096 / TPB; ++i) sm.hist[i * TPB + t] = 0u;
        BARRIER();
#pragma unroll
        for (int c = 0; c < NCH; ++c) {
            float4 v = sm.row[c * CHF4 + t];
            float vals[4] = { v.x, v.y, v.z, v.w };
#pragma unroll
            for (int e = 0; e < 4; ++e) {
                uint32_t key = f2k(vals[e]);
                if ((key >> 20) == B1) atomicAdd(&sm.hist[(key >> 8) & 0xFFFu], 1u);
            }
        }
        BARRIER();
        select4096(sm, need2, t);
        const uint32_t B2 = sm.bin;
        const uint32_t need3 = sm.rem;

        if (t < 256) sm.hist[t] = 0u;
        BARRIER();
        const uint32_t pref = (B1 << 12) | B2;
#pragma unroll
        for (int c = 0; c < NCH; ++c) {
            float4 v = sm.row[c * CHF4 + t];
            float vals[4] = { v.x, v.y, v.z, v.w };
#pragma unroll
            for (int e = 0; e < 4; ++e) {
                uint32_t key = f2k(vals[e]);
                if ((key >> 8) == pref) atomicAdd(&sm.hist[key & 0xFFu], 1u);
            }
        }
        BARRIER();
        select256(sm, need3, t);
        K = (pref << 8) | sm.bin;
        eqneed = sm.rem;
        eqcnt = sm.eqcnt;
    }

    // ===== phase C: final write; recycle each slot for next-row DMA =====
    if (eqcnt == eqneed) {
#pragma unroll
        for (int c = 0; c < NCH; ++c) {
            float4 v = sm.row[c * CHF4 + t];
            float ov[4] = {
                (f2k(v.x) >= K) ? v.x : 0.0f, (f2k(v.y) >= K) ? v.y : 0.0f,
                (f2k(v.z) >= K) ? v.z : 0.0f, (f2k(v.w) >= K) ? v.w : 0.0f };
            BARRIER();                      // all waves done reading slot c
            if (xnext) dma_chunk(xnext, sm, c, t);   // re-target slot c
            float4 o; o.x = ov[0]; o.y = ov[1]; o.z = ov[2]; o.w = ov[3];
            outr4[c * CHF4 + t] = o;
        }
    } else if (C <= CAP) {
        // rare ties: rank own ==K elements against the candidate list
#pragma unroll
        for (int c = 0; c < NCH; ++c) {
            float4 v = sm.row[c * CHF4 + t];
            float vals[4] = { v.x, v.y, v.z, v.w };
            float ov[4];
#pragma unroll
            for (int e = 0; e < 4; ++e) {
                uint32_t key = f2k(vals[e]);
                bool take = key > K;
                if (key == K) {
                    uint32_t col = (uint32_t)((c * CHF4 + t) * 4 + e);
                    uint32_t rank = 0;
                    for (uint32_t m = 0; m < C; ++m)
                        if (sm.cand_key[m] == K && sm.cand_col[m] < col) ++rank;
                    take = (rank < eqneed);
                }
                ov[e] = take ? vals[e] : 0.0f;
            }
            BARRIER();
            if (xnext) dma_chunk(xnext, sm, c, t);
            float4 o; o.x = ov[0]; o.y = ov[1]; o.z = ov[2]; o.w = ov[3];
            outr4[c * CHF4 + t] = o;
        }
    } else {
        // overflow + ties: ordered selection among ==K by lowest column
        if (t == 0) sm.chunk_base = 0u;
        BARRIER();
        const int lane = t & 63;
        const int wid = t >> 6;
        for (int c = 0; c < NCH; ++c) {
            float4 v = sm.row[c * CHF4 + t];
            float vals[4] = { v.x, v.y, v.z, v.w };
            uint32_t keys[4];
            uint32_t e0 = 0;
#pragma unroll
            for (int e = 0; e < 4; ++e) { keys[e] = f2k(vals[e]); e0 += (keys[e] == K) ? 1u : 0u; }
            uint32_t pre = e0;
            for (int off = 1; off < 64; off <<= 1) {
                uint32_t n = (uint32_t)__shfl_up((int)pre, off, 64);
                if (lane >= off) pre += n;
            }
            if (lane == 63) sm.wtot[wid] = pre;
            BARRIER();
            uint32_t before = sm.chunk_base + (pre - e0);
            for (int w = 0; w < wid; ++w) before += sm.wtot[w];
            float ov[4];
#pragma unroll
            for (int e = 0; e < 4; ++e) {
                bool take = keys[e] > K;
                if (keys[e] == K) { take = (before < eqneed); ++before; }
                ov[e] = take ? vals[e] : 0.0f;
            }
            float4 o; o.x = ov[0]; o.y = ov[1]; o.z = ov[2]; o.w = ov[3];
            outr4[c * CHF4 + t] = o;
            BARRIER();
            if (t == 0) {
                uint32_t s2 = sm.chunk_base;
#pragma unroll
                for (int w = 0; w < NW; ++w) s2 += sm.wtot[w];
                sm.chunk_base = s2;
            }
            BARRIER();
        }
        BARRIER();
        if (xnext) {
#pragma unroll
            for (int c = 0; c < NCH; ++c) dma_chunk(xnext, sm, c, t);
        }
    }
}

__global__ __launch_bounds__(TPB) void topk_scatter_kernel(
    const float* __restrict__ x,
    const int* __restrict__ kp,
    float* __restrict__ out,
    int nrows)
{
    __shared__ Sm sm;
    const int t = threadIdx.x;
    const uint32_t k = (uint32_t)kp[0];
    const int gs = (int)gridDim.x;

    if (k == 0u || k >= (uint32_t)HSZ) {  // degenerate: all zeros or identity
        for (int r = (int)blockIdx.x; r < nrows; r += gs) {
            const float4* xr4 = reinterpret_cast<const float4*>(x + (size_t)r * HSZ);
            float4* outr4 = reinterpret_cast<float4*>(out + (size_t)r * HSZ);
#pragma unroll
            for (int c = 0; c < NCH; ++c) {
                float4 o;
                if (k == 0u) { o.x = o.y = o.z = o.w = 0.0f; }
                else o = xr4[c * CHF4 + t];
                outr4[c * CHF4 + t] = o;
            }
        }
        return;
    }

    int r = (int)blockIdx.x;
    if (r >= nrows) return;

    // prologue: DMA all chunks of the first row (no VGPR staging at all)
#pragma unroll
    for (int c = 0; c < NCH; ++c) dma_chunk(x + (size_t)r * HSZ, sm, c, t);

    for (;;) {
        WAIT_VM0_BARRIER();   // this row's chunks landed in LDS (all waves)
        const int rn = r + gs;
        const float* xnext = (rn < nrows) ? (x + (size_t)rn * HSZ) : nullptr;
        process_row(out + (size_t)r * HSZ, xnext, k, sm, t);
        if (rn >= nrows) break;
        r = rn;
    }
}

extern "C" void kernel_launch(void* const* d_in, const int* in_sizes, int n_in,
                              void* d_out, int out_size, void* d_ws, size_t ws_size,
                              hipStream_t stream) {
    const float* x = (const float*)d_in[0];
    const int* kp = (const int*)d_in[1];
    float* out = (float*)d_out;
    const int total = in_sizes[0];
    const int rows = total / HSZ;        // 8192
    int grid = rows < 256 ? rows : 256;  // 1 persistent block per CU (LDS-bound)
    topk_scatter_kernel<<<grid, TPB, 0, stream>>>(x, kp, out, rows);
}